// Round 5
// baseline (159.470 us; speedup 1.0000x reference)
//
#include <hip/hip_runtime.h>
#include <cstdint>

// Problem constants (fixed by setup_inputs)
constexpr int kB = 2;
constexpr int kN = 21760;
constexpr int kC = 256;
constexpr int kH = 8;
constexpr int kS = 21760;    // total sample-map area
constexpr int kM = kB * kN;  // 43520 rows
constexpr int kMT = 340;     // m-tiles (kM / 128)

typedef __attribute__((ext_vector_type(8))) short bf16x8;   // MFMA A/B frag (4 VGPR)
typedef __attribute__((ext_vector_type(4))) float f32x4;    // MFMA C/D frag
typedef __attribute__((ext_vector_type(8))) unsigned short us8;

__device__ __forceinline__ float bf2f(unsigned short u) {
  return __uint_as_float(((unsigned int)u) << 16);
}
__device__ __forceinline__ unsigned short f2bf(float f) {
  unsigned int u = __float_as_uint(f);
  u += 0x7fffu + ((u >> 16) & 1u);
  return (unsigned short)(u >> 16);
}
__device__ __forceinline__ float blo(unsigned int v) { return __uint_as_float(v << 16); }
__device__ __forceinline__ float bhi(unsigned int v) { return __uint_as_float(v & 0xffff0000u); }
__device__ __forceinline__ unsigned int cvt_pk_bf16(float lo, float hi) {
  unsigned int r;
  asm("v_cvt_pk_bf16_f32 %0, %1, %2" : "=v"(r) : "v"(lo), "v"(hi));
  return r;   // low ushort = bf16(lo), high ushort = bf16(hi)  [RNE]
}
__device__ __forceinline__ void gld_lds16(const unsigned short* g, unsigned short* l) {
  __builtin_amdgcn_global_load_lds(
      (const __attribute__((address_space(1))) unsigned int*)g,
      (__attribute__((address_space(3))) unsigned int*)l, 16, 0, 0);
}

// ---------------------------------------------------------------------------
// Weights: f32 [K=256][N] -> bf16 transposed [N][K], rows pre-swizzled
// (element k stored at k ^ ((n&7)<<3)).
// ---------------------------------------------------------------------------
__global__ __launch_bounds__(256) void prep_weights(
    const float* __restrict__ Woff, const float* __restrict__ Wattn,
    const float* __restrict__ Wval, const float* __restrict__ Wout,
    unsigned short* __restrict__ BtOff, unsigned short* __restrict__ BtAttn,
    unsigned short* __restrict__ BtVal, unsigned short* __restrict__ BtOut)
{
  const int tid = blockIdx.x * 256 + threadIdx.x;   // 896 rows * 32
  const int r = tid >> 5;
  const int kb = (tid & 31) * 8;
  const float* W; unsigned short* Bt; int n, Nn;
  if (r < 256)      { W = Woff;  Bt = BtOff;  n = r;       Nn = 256; }
  else if (r < 384) { W = Wattn; Bt = BtAttn; n = r - 256; Nn = 128; }
  else if (r < 640) { W = Wval;  Bt = BtVal;  n = r - 384; Nn = 256; }
  else              { W = Wout;  Bt = BtOut;  n = r - 640; Nn = 256; }
  us8 o;
#pragma unroll
  for (int i = 0; i < 8; ++i) o[i] = f2bf(W[(size_t)(kb + i) * Nn + n]);
  *(us8*)&Bt[(size_t)n * 256 + (kb ^ ((n & 7) << 3))] = o;
}

// ---------------------------------------------------------------------------
// Unified bf16-MFMA GEMM over A[kM,256] with 128x128 tiles, BK=64.
// KIND 0: A = f32 in_feats, B = BtOA [384][256] (off ++ attn), NT=3 n-tiles.
//         cols 0..255 -> off head-major [8][kM][32]; 256..383 -> attn
//         head-major [8][kM][16].  bias0 = b_off, bias1 = b_attn.
// KIND 1: A = f32 sfeats, B = BtVal, NT=2. out = value head-major
//         [16][kS][32] bf16.
// KIND 2: A = bf16 wgt (rows pre-swizzled), B = BtOut, NT=2. out = f32 plain.
// blockIdx decode co-locates all n-tiles of one m-tile on the same XCD
// (ids 8 apart; dispatch round-robins XCDs) so A-tile re-reads hit L2.
// A-f32 path: reg-stage 32 floats/thread, cvt_pk_bf16 -> swizzled ds_write.
// ---------------------------------------------------------------------------
template <int KIND>
__global__ __launch_bounds__(256) void gemm_top(
    const void* __restrict__ Aip,
    const unsigned short* __restrict__ Bt,
    const float* __restrict__ bias0, const float* __restrict__ bias1,
    void* __restrict__ out0, void* __restrict__ out1)
{
  constexpr int NT = (KIND == 0) ? 3 : 2;
  const int bid = blockIdx.x;
  const int x = bid & 7;
  const int slot = bid >> 3;
  const int nt = slot % NT;
  const int mh = slot / NT;
  const int m = mh * 8 + x;
  if (m >= kMT) return;
  const int m0 = m * 128, n0 = nt * 128;

  __shared__ unsigned short As[128 * 64];
  __shared__ unsigned short Bs[128 * 64];
  const int t = threadIdx.x;
  const int w = t >> 6, l = t & 63;
  const int wm = w >> 1, wn = w & 1;

  f32x4 acc[4][4] = {};

  const int srow = l >> 3;        // gld_lds staging row within chunk
  const int skb  = (l & 7) * 8;   // ushort offset within 64-k block

  // f32 A staging mapping: thread -> (row, half of 64-k)
  const int arow = t >> 1;
  const int akh  = (t & 1) << 5;  // 0 or 32
  const float* af = (const float*)Aip + (size_t)(m0 + arow) * 256 + akh;
  const unsigned short* abf = (const unsigned short*)Aip;

  for (int kt = 0; kt < 256; kt += 64) {
    if (KIND == 2) {
      // A already bf16 + row-swizzled: async copy
#pragma unroll
      for (int i = 0; i < 4; ++i) {
        const int c = i * 4 + w;
        const int row = c * 8 + srow;
        gld_lds16(abf + (size_t)(m0 + row) * 256 + kt + skb, &As[c * 512]);
      }
    } else {
      // A f32: reg-stage + convert + swizzled ds_write
      float4 f[8];
#pragma unroll
      for (int i = 0; i < 8; ++i) f[i] = *(const float4*)&af[kt + i * 4];
      unsigned int u[16];
#pragma unroll
      for (int i = 0; i < 16; ++i)
        u[i] = cvt_pk_bf16(f[i >> 1][(i & 1) * 2], f[i >> 1][(i & 1) * 2 + 1]);
      const int swz = (arow & 7) << 3;
#pragma unroll
      for (int i = 0; i < 4; ++i) {
        uint4 o; o.x = u[i*4]; o.y = u[i*4+1]; o.z = u[i*4+2]; o.w = u[i*4+3];
        *(uint4*)&As[arow * 64 + ((akh + 8 * i) ^ swz)] = o;
      }
    }
#pragma unroll
    for (int i = 0; i < 4; ++i) {
      const int c = i * 4 + w;
      const int row = c * 8 + srow;
      gld_lds16(Bt + (size_t)(n0 + row) * 256 + kt + skb, &Bs[c * 512]);
    }
    __syncthreads();

#pragma unroll
    for (int s = 0; s < 2; ++s) {
      bf16x8 afr[4], bfr[4];
      const int kf = s * 32 + ((l >> 4) * 8);
#pragma unroll
      for (int i = 0; i < 4; ++i) {
        const int row = wm * 64 + i * 16 + (l & 15);
        afr[i] = *(const bf16x8*)&As[row * 64 + (kf ^ ((row & 7) << 3))];
      }
#pragma unroll
      for (int j = 0; j < 4; ++j) {
        const int col = wn * 64 + j * 16 + (l & 15);
        bfr[j] = *(const bf16x8*)&Bs[col * 64 + (kf ^ ((col & 7) << 3))];
      }
#pragma unroll
      for (int i = 0; i < 4; ++i)
#pragma unroll
        for (int j = 0; j < 4; ++j)
          acc[i][j] = __builtin_amdgcn_mfma_f32_16x16x32_bf16(afr[i], bfr[j], acc[i][j], 0, 0, 0);
    }
    __syncthreads();
  }

  // epilogue: C/D map col = lane&15, row = (lane>>4)*4 + reg
  const int lr = l >> 4;
#pragma unroll
  for (int j = 0; j < 4; ++j) {
    const int col = n0 + wn * 64 + j * 16 + (l & 15);
    const float bv = (KIND == 0 && n0 == 256) ? bias1[col - 256] : bias0[col];
#pragma unroll
    for (int i = 0; i < 4; ++i) {
      const int rbase = m0 + wm * 64 + i * 16 + lr * 4;
#pragma unroll
      for (int r = 0; r < 4; ++r) {
        const float v = acc[i][j][r] + bv;
        const int row = rbase + r;
        if (KIND == 2) {
          ((float*)out0)[(size_t)row * 256 + col] = v;
        } else if (KIND == 1) {
          const int bb = row >= kS;
          const int s2 = row - bb * kS;
          ((unsigned short*)out0)[((size_t)(bb * 8 + (col >> 5)) * kS + s2) * 32 + (col & 31)] = f2bf(v);
        } else if (col < 256) {   // off head-major [8][kM][32]
          ((unsigned short*)out0)[((size_t)(col >> 5) * kM + row) * 32 + (col & 31)] = f2bf(v);
        } else {                  // attn head-major [8][kM][16]
          const int c2 = col - 256;
          ((unsigned short*)out1)[((size_t)(c2 >> 4) * kM + row) * 16 + (c2 & 15)] = f2bf(v);
        }
      }
    }
  }
}

// ---------------------------------------------------------------------------
// MSDA core, plane-partitioned (unchanged from round 4 — proven).
// Block = 16 queries x ONE (b,h) plane; grid = chunk*16 + plane, so plane
// p's blocks land on XCD p&7 -> per-XCD value working set 2 planes, L2-hot.
// ---------------------------------------------------------------------------
__global__ __launch_bounds__(256) void msda_kernel(
    const unsigned short* __restrict__ off_hm,   // [8][kM][32] bf16 head-major
    const unsigned short* __restrict__ attn_hm,  // [8][kM][16] bf16 head-major
    const unsigned short* __restrict__ val_bf,   // [16][kS][32] bf16 head-major
    const float* __restrict__ priors,            // [kM][8]
    unsigned short* __restrict__ wgt)            // [kM][256] bf16 swizzled
{
  __shared__ int s_rec[16 * 136];
  const int bid = blockIdx.x;
  const int plane = bid & 15;          // b*8 + h
  const int chunk = bid >> 4;
  const int b = plane >> 3, h = plane & 7;
  const int t = threadIdx.x;
  const int ql = t >> 4;
  const int q = b * kN + chunk * 16 + ql;

  { // ---- phase 1 ----
    const int j = t & 15;
    const int lv = j >> 2;

    const float lgt = bf2f(attn_hm[((size_t)h * kM + q) * 16 + j]);
    float mx = lgt;
#pragma unroll
    for (int m = 8; m; m >>= 1) mx = fmaxf(mx, __shfl_xor(mx, m, 16));
    const float p = __expf(lgt - mx);
    float sum = p;
#pragma unroll
    for (int m = 8; m; m >>= 1) sum += __shfl_xor(sum, m, 16);
    const float wN = p / sum;

    const unsigned int oo = *(const unsigned int*)&off_hm[((size_t)h * kM + q) * 32 + j * 2];
    const float ox = blo(oo);
    const float oy = bhi(oo);
    const float2 pr = *(const float2*)&priors[(size_t)q * 8 + lv * 2];

    const int Wl = 128 >> lv;
    const float fW = (float)Wl;
    const float lx = fmaf(pr.x, fW, ox) - 0.5f;
    const float ly = fmaf(pr.y, fW, oy) - 0.5f;
    const float x0f = floorf(lx), y0f = floorf(ly);
    const float wx1 = lx - x0f, wy1 = ly - y0f;
    const float wx0 = 1.f - wx1, wy0 = 1.f - wy1;
    const int x0 = (int)x0f, y0 = (int)y0f;
    const int start = (int)((0x5400500040000000ull >> (16 * lv)) & 0xffff); // {0,16384,20480,21504}

    const bool vx0 = (x0 >= 0) & (x0 < Wl);
    const bool vx1 = (x0 + 1 >= 0) & (x0 + 1 < Wl);
    const bool vy0 = (y0 >= 0) & (y0 < Wl);
    const bool vy1 = (y0 + 1 >= 0) & (y0 + 1 < Wl);
    const int xc0 = min(max(x0, 0), Wl - 1);
    const int xc1 = min(max(x0 + 1, 0), Wl - 1);
    const int yc0 = min(max(y0, 0), Wl - 1);
    const int yc1 = min(max(y0 + 1, 0), Wl - 1);

    const int rt = start + yc0 * Wl;   // row bases (elements)
    const int rb = start + yc1 * Wl;

    int4 r0, r1;
    r0.x = (rt + xc0) * 64; r0.y = __float_as_int((vx0 & vy0) ? wN * wx0 * wy0 : 0.f);
    r0.z = (rt + xc1) * 64; r0.w = __float_as_int((vx1 & vy0) ? wN * wx1 * wy0 : 0.f);
    r1.x = (rb + xc0) * 64; r1.y = __float_as_int((vx0 & vy1) ? wN * wx0 * wy1 : 0.f);
    r1.z = (rb + xc1) * 64; r1.w = __float_as_int((vx1 & vy1) ? wN * wx1 * wy1 : 0.f);

    const int base = ql * 136 + j * 8;
    *(int4*)&s_rec[base] = r0;
    *(int4*)&s_rec[base + 4] = r1;
  }
  __syncthreads();

  // ---- phase 2 ----
  const int lane = t & 15;
  const int c = lane >> 2;        // corner: 0=TL 1=TR 2=BL 3=BR
  const int k = lane & 3;         // 16B chunk (8 channels)
  const char* plane_base = (const char*)val_bf + (size_t)plane * kS * 64 + k * 16;
  const int* rp = &s_rec[ql * 136 + c * 2];

  float a0 = 0.f, a1 = 0.f, a2 = 0.f, a3 = 0.f;
  float a4 = 0.f, a5 = 0.f, a6 = 0.f, a7 = 0.f;
#pragma unroll
  for (int j = 0; j < 16; ++j) {
    const int2 r = *(const int2*)&rp[j * 8];
    const float w = __int_as_float(r.y);
    const uint4 v = *(const uint4*)(plane_base + r.x);
    a0 = fmaf(w, blo(v.x), a0); a1 = fmaf(w, bhi(v.x), a1);
    a2 = fmaf(w, blo(v.y), a2); a3 = fmaf(w, bhi(v.y), a3);
    a4 = fmaf(w, blo(v.z), a4); a5 = fmaf(w, bhi(v.z), a5);
    a6 = fmaf(w, blo(v.w), a6); a7 = fmaf(w, bhi(v.w), a7);
  }

  // fold the 4 corners (lane bits 2-3)
#pragma unroll
  for (int m = 4; m <= 8; m <<= 1) {
    a0 += __shfl_xor(a0, m); a1 += __shfl_xor(a1, m);
    a2 += __shfl_xor(a2, m); a3 += __shfl_xor(a3, m);
    a4 += __shfl_xor(a4, m); a5 += __shfl_xor(a5, m);
    a6 += __shfl_xor(a6, m); a7 += __shfl_xor(a7, m);
  }

  if (c == 0) {
    const int c0 = h * 32 + k * 8;                    // ushort index in row
    const int dst = c0 ^ ((q & 7) << 3);
    uint4 o;
    o.x = (unsigned int)f2bf(a0) | ((unsigned int)f2bf(a1) << 16);
    o.y = (unsigned int)f2bf(a2) | ((unsigned int)f2bf(a3) << 16);
    o.z = (unsigned int)f2bf(a4) | ((unsigned int)f2bf(a5) << 16);
    o.w = (unsigned int)f2bf(a6) | ((unsigned int)f2bf(a7) << 16);
    *(uint4*)&wgt[(size_t)q * 256 + dst] = o;
  }
}

// ---------------------------------------------------------------------------
// launch
// ---------------------------------------------------------------------------
extern "C" void kernel_launch(void* const* d_in, const int* in_sizes, int n_in,
                              void* d_out, int out_size, void* d_ws, size_t ws_size,
                              hipStream_t stream) {
  const float* in_feats = (const float*)d_in[0];
  const float* priors   = (const float*)d_in[1];
  const float* sfeats   = (const float*)d_in[2];
  const float* W_off  = (const float*)d_in[5];
  const float* b_off  = (const float*)d_in[6];
  const float* W_attn = (const float*)d_in[7];
  const float* b_attn = (const float*)d_in[8];
  const float* W_val  = (const float*)d_in[9];
  const float* b_val  = (const float*)d_in[10];
  const float* W_out  = (const float*)d_in[11];
  const float* b_out  = (const float*)d_in[12];
  float* out = (float*)d_out;

  // workspace (bf16 ushorts), ~78 MB
  unsigned short* off_hm  = (unsigned short*)d_ws;          // [8][kM][32]
  unsigned short* attn_hm = off_hm  + (size_t)kM * 256;     // [8][kM][16]
  unsigned short* val_bf  = attn_hm + (size_t)kM * 128;     // [16][kS][32]
  unsigned short* wgt_bf  = val_bf  + (size_t)kM * 256;     // [kM][256] swizzled
  unsigned short* BtOff   = wgt_bf  + (size_t)kM * 256;     // 256*256  (BtOA rows 0-255)
  unsigned short* BtAttn  = BtOff   + 256 * 256;            // 128*256  (BtOA rows 256-383)
  unsigned short* BtVal   = BtAttn  + 128 * 256;            // 256*256
  unsigned short* BtOut   = BtVal   + 256 * 256;            // 256*256

  const dim3 blk(256);

  prep_weights<<<dim3(112), blk, 0, stream>>>(
      W_off, W_attn, W_val, W_out, BtOff, BtAttn, BtVal, BtOut);

  // fused off+attn GEMM: B = BtOff++BtAttn (contiguous), NT=3
  gemm_top<0><<<dim3(8 * 3 * 43), blk, 0, stream>>>(
      in_feats, BtOff, b_off, b_attn, off_hm, attn_hm);
  // value GEMM, NT=2
  gemm_top<1><<<dim3(8 * 2 * 43), blk, 0, stream>>>(
      sfeats, BtVal, b_val, nullptr, val_bf, nullptr);

  msda_kernel<<<dim3(kM / 2), blk, 0, stream>>>(off_hm, attn_hm, val_bf, priors, wgt_bf);

  // output GEMM, NT=2
  gemm_top<2><<<dim3(8 * 2 * 43), blk, 0, stream>>>(
      wgt_bf, BtOut, b_out, nullptr, out, nullptr);
}

// Round 6
// 150.875 us; speedup vs baseline: 1.0570x; 1.0570x over previous
//
#include <hip/hip_runtime.h>
#include <cstdint>

// Problem constants (fixed by setup_inputs)
constexpr int kB = 2;
constexpr int kN = 21760;
constexpr int kC = 256;
constexpr int kH = 8;
constexpr int kS = 21760;    // total sample-map area
constexpr int kM = kB * kN;  // 43520 rows
constexpr int kMT = 340;     // m-tiles (kM / 128)

typedef __attribute__((ext_vector_type(8))) short bf16x8;   // MFMA A/B frag (4 VGPR)
typedef __attribute__((ext_vector_type(4))) float f32x4;    // MFMA C/D frag
typedef __attribute__((ext_vector_type(8))) unsigned short us8;

__device__ __forceinline__ float bf2f(unsigned short u) {
  return __uint_as_float(((unsigned int)u) << 16);
}
__device__ __forceinline__ unsigned short f2bf(float f) {
  unsigned int u = __float_as_uint(f);
  u += 0x7fffu + ((u >> 16) & 1u);
  return (unsigned short)(u >> 16);
}
__device__ __forceinline__ float blo(unsigned int v) { return __uint_as_float(v << 16); }
__device__ __forceinline__ float bhi(unsigned int v) { return __uint_as_float(v & 0xffff0000u); }
__device__ __forceinline__ void gld_lds16(const unsigned short* g, unsigned short* l) {
  __builtin_amdgcn_global_load_lds(
      (const __attribute__((address_space(1))) unsigned int*)g,
      (__attribute__((address_space(3))) unsigned int*)l, 16, 0, 0);
}

// ---------------------------------------------------------------------------
// Fused convert + weight prep.
// Blocks [0, 10880): in_feats & sfeats f32 [kM][256] -> bf16, rows
//   pre-swizzled (element k at k ^ ((m&7)<<3)) for GEMM LDS staging.
// Blocks [10880, 10992): weights f32 [K][N] -> bf16 transposed [N][K],
//   rows pre-swizzled the same way.
// ---------------------------------------------------------------------------
__global__ __launch_bounds__(256) void convprep(
    const float* __restrict__ a, const float* __restrict__ b,
    unsigned short* __restrict__ da, unsigned short* __restrict__ db,
    const float* __restrict__ Woff, const float* __restrict__ Wattn,
    const float* __restrict__ Wval, const float* __restrict__ Wout,
    unsigned short* __restrict__ BtOff, unsigned short* __restrict__ BtAttn,
    unsigned short* __restrict__ BtVal, unsigned short* __restrict__ BtOut)
{
  const int bid = blockIdx.x;
  if (bid < 10880) {
    const int tid = bid * 256 + threadIdx.x;
    const int half = kM * 32;
    const float* src; unsigned short* dst; int id;
    if (tid < half) { src = a; dst = da; id = tid; }
    else            { src = b; dst = db; id = tid - half; }
    const int m = id >> 5;
    const int kb = (id & 31) * 8;
    const float4 x0 = *(const float4*)&src[(size_t)m * 256 + kb];
    const float4 x1 = *(const float4*)&src[(size_t)m * 256 + kb + 4];
    us8 o;
    o[0] = f2bf(x0.x); o[1] = f2bf(x0.y); o[2] = f2bf(x0.z); o[3] = f2bf(x0.w);
    o[4] = f2bf(x1.x); o[5] = f2bf(x1.y); o[6] = f2bf(x1.z); o[7] = f2bf(x1.w);
    *(us8*)&dst[(size_t)m * 256 + (kb ^ ((m & 7) << 3))] = o;
  } else {
    const int tid = (bid - 10880) * 256 + threadIdx.x;   // 896 rows * 32
    const int r = tid >> 5;
    const int kb = (tid & 31) * 8;
    const float* W; unsigned short* Bt; int n, Nn;
    if (r < 256)      { W = Woff;  Bt = BtOff;  n = r;       Nn = 256; }
    else if (r < 384) { W = Wattn; Bt = BtAttn; n = r - 256; Nn = 128; }
    else if (r < 640) { W = Wval;  Bt = BtVal;  n = r - 384; Nn = 256; }
    else              { W = Wout;  Bt = BtOut;  n = r - 640; Nn = 256; }
    us8 o;
#pragma unroll
    for (int i = 0; i < 8; ++i) o[i] = f2bf(W[(size_t)(kb + i) * Nn + n]);
    *(us8*)&Bt[(size_t)n * 256 + (kb ^ ((n & 7) << 3))] = o;
  }
}

// ---------------------------------------------------------------------------
// Shared MFMA tile core: A,Bt bf16 row-swizzled, 128x128 tile, BK=64,
// all staging via async global_load_lds (proven round-4 path).
// acc must be zero-initialized by caller; returns with acc filled.
// ---------------------------------------------------------------------------
__device__ __forceinline__ void mfma_tile_256(
    const unsigned short* __restrict__ A, const unsigned short* __restrict__ Bt,
    int m0, int n0, int t, unsigned short* As, unsigned short* Bs,
    f32x4 (&acc)[4][4])
{
  const int w = t >> 6, l = t & 63;
  const int wm = w >> 1, wn = w & 1;
  const int srow = l >> 3;
  const int skb  = (l & 7) * 8;

  for (int kt = 0; kt < 256; kt += 64) {
#pragma unroll
    for (int i = 0; i < 4; ++i) {
      const int c = i * 4 + w;
      const int row = c * 8 + srow;
      gld_lds16(A + (size_t)(m0 + row) * 256 + kt + skb, &As[c * 512]);
    }
#pragma unroll
    for (int i = 0; i < 4; ++i) {
      const int c = i * 4 + w;
      const int row = c * 8 + srow;
      gld_lds16(Bt + (size_t)(n0 + row) * 256 + kt + skb, &Bs[c * 512]);
    }
    __syncthreads();

#pragma unroll
    for (int s = 0; s < 2; ++s) {
      bf16x8 afr[4], bfr[4];
      const int kf = s * 32 + ((l >> 4) * 8);
#pragma unroll
      for (int i = 0; i < 4; ++i) {
        const int row = wm * 64 + i * 16 + (l & 15);
        afr[i] = *(const bf16x8*)&As[row * 64 + (kf ^ ((row & 7) << 3))];
      }
#pragma unroll
      for (int j = 0; j < 4; ++j) {
        const int col = wn * 64 + j * 16 + (l & 15);
        bfr[j] = *(const bf16x8*)&Bs[col * 64 + (kf ^ ((col & 7) << 3))];
      }
#pragma unroll
      for (int i = 0; i < 4; ++i)
#pragma unroll
        for (int j = 0; j < 4; ++j)
          acc[i][j] = __builtin_amdgcn_mfma_f32_16x16x32_bf16(afr[i], bfr[j], acc[i][j], 0, 0, 0);
    }
    __syncthreads();
  }
}

// ---------------------------------------------------------------------------
// Lead GEMM: one launch covering BOTH the fused off+attn GEMM and the value
// GEMM. grid = 8 * 215:
//   x = bid&7 (m&7), slot = bid>>3 in [0,215):
//   slot <  129: mode 0 (A=in_bf, B=BtOA 384 cols), nt = slot%3, mh = slot/3
//   slot >= 129: mode 1 (A=s_bf,  B=BtVal 256 cols), nt = s2%2, mh = s2/2
// Same-m n-tile blocks sit 8 ids apart -> same XCD (round-robin dispatch)
// -> A-tile re-reads are L2 hits.
// Outputs head-major for msda: off [8][kM][32], attn [8][kM][16],
// value [16][kS][32].
// ---------------------------------------------------------------------------
__global__ __launch_bounds__(256) void gemm_lead(
    const unsigned short* __restrict__ in_bf,
    const unsigned short* __restrict__ s_bf,
    const unsigned short* __restrict__ BtOA,
    const unsigned short* __restrict__ BtVal,
    const float* __restrict__ b_off, const float* __restrict__ b_attn,
    const float* __restrict__ b_val,
    unsigned short* __restrict__ off_hm,
    unsigned short* __restrict__ attn_hm,
    unsigned short* __restrict__ val_hm)
{
  const int bid = blockIdx.x;
  const int x = bid & 7;
  const int slot = bid >> 3;
  int mode, nt, mh;
  if (slot < 129) { mode = 0; nt = slot % 3; mh = slot / 3; }
  else            { mode = 1; const int s2 = slot - 129; nt = s2 % 2; mh = s2 / 2; }
  const int m = mh * 8 + x;
  if (m >= kMT) return;
  const int m0 = m * 128, n0 = nt * 128;

  __shared__ unsigned short As[128 * 64];
  __shared__ unsigned short Bs[128 * 64];
  const int t = threadIdx.x;

  f32x4 acc[4][4] = {};
  mfma_tile_256(mode ? s_bf : in_bf, mode ? BtVal : BtOA, m0, n0, t, As, Bs, acc);

  const int w = t >> 6, l = t & 63;
  const int wm = w >> 1, wn = w & 1;
  const int lr = l >> 4;
#pragma unroll
  for (int j = 0; j < 4; ++j) {
    const int col = n0 + wn * 64 + j * 16 + (l & 15);
    const float bv = mode ? b_val[col] : (col < 256 ? b_off[col] : b_attn[col - 256]);
#pragma unroll
    for (int i = 0; i < 4; ++i) {
      const int rbase = m0 + wm * 64 + i * 16 + lr * 4;
#pragma unroll
      for (int r = 0; r < 4; ++r) {
        const float v = acc[i][j][r] + bv;
        const int row = rbase + r;
        if (mode == 1) {          // value head-major [16][kS][32]
          const int bb = row >= kS;
          const int s2 = row - bb * kS;
          val_hm[((size_t)(bb * 8 + (col >> 5)) * kS + s2) * 32 + (col & 31)] = f2bf(v);
        } else if (col < 256) {   // off head-major [8][kM][32]
          off_hm[((size_t)(col >> 5) * kM + row) * 32 + (col & 31)] = f2bf(v);
        } else {                  // attn head-major [8][kM][16]
          const int c2 = col - 256;
          attn_hm[((size_t)(c2 >> 4) * kM + row) * 16 + (c2 & 15)] = f2bf(v);
        }
      }
    }
  }
}

// ---------------------------------------------------------------------------
// Output GEMM: A = bf16 wgt (rows pre-swizzled), B = BtOut, f32 plain out.
// grid = 8 * 2 * 43, XCD-co-located decode.
// ---------------------------------------------------------------------------
__global__ __launch_bounds__(256) void gemm_out(
    const unsigned short* __restrict__ wgt,
    const unsigned short* __restrict__ BtOut,
    const float* __restrict__ b_out,
    float* __restrict__ out)
{
  const int bid = blockIdx.x;
  const int x = bid & 7;
  const int slot = bid >> 3;
  const int nt = slot % 2;
  const int mh = slot / 2;
  const int m = mh * 8 + x;
  if (m >= kMT) return;
  const int m0 = m * 128, n0 = nt * 128;

  __shared__ unsigned short As[128 * 64];
  __shared__ unsigned short Bs[128 * 64];
  const int t = threadIdx.x;

  f32x4 acc[4][4] = {};
  mfma_tile_256(wgt, BtOut, m0, n0, t, As, Bs, acc);

  const int w = t >> 6, l = t & 63;
  const int wm = w >> 1, wn = w & 1;
  const int lr = l >> 4;
#pragma unroll
  for (int j = 0; j < 4; ++j) {
    const int col = n0 + wn * 64 + j * 16 + (l & 15);
    const float bv = b_out[col];
#pragma unroll
    for (int i = 0; i < 4; ++i) {
      const int rbase = m0 + wm * 64 + i * 16 + lr * 4;
#pragma unroll
      for (int r = 0; r < 4; ++r)
        out[(size_t)(rbase + r) * 256 + col] = acc[i][j][r] + bv;
    }
  }
}

// ---------------------------------------------------------------------------
// MSDA core, plane-partitioned (unchanged — proven).
// Block = 16 queries x ONE (b,h) plane; grid = chunk*16 + plane, so plane
// p's blocks land on XCD p&7 -> per-XCD value working set 2 planes, L2-hot.
// ---------------------------------------------------------------------------
__global__ __launch_bounds__(256) void msda_kernel(
    const unsigned short* __restrict__ off_hm,   // [8][kM][32] bf16 head-major
    const unsigned short* __restrict__ attn_hm,  // [8][kM][16] bf16 head-major
    const unsigned short* __restrict__ val_bf,   // [16][kS][32] bf16 head-major
    const float* __restrict__ priors,            // [kM][8]
    unsigned short* __restrict__ wgt)            // [kM][256] bf16 swizzled
{
  __shared__ int s_rec[16 * 136];
  const int bid = blockIdx.x;
  const int plane = bid & 15;          // b*8 + h
  const int chunk = bid >> 4;
  const int b = plane >> 3, h = plane & 7;
  const int t = threadIdx.x;
  const int ql = t >> 4;
  const int q = b * kN + chunk * 16 + ql;

  { // ---- phase 1 ----
    const int j = t & 15;
    const int lv = j >> 2;

    const float lgt = bf2f(attn_hm[((size_t)h * kM + q) * 16 + j]);
    float mx = lgt;
#pragma unroll
    for (int m = 8; m; m >>= 1) mx = fmaxf(mx, __shfl_xor(mx, m, 16));
    const float p = __expf(lgt - mx);
    float sum = p;
#pragma unroll
    for (int m = 8; m; m >>= 1) sum += __shfl_xor(sum, m, 16);
    const float wN = p / sum;

    const unsigned int oo = *(const unsigned int*)&off_hm[((size_t)h * kM + q) * 32 + j * 2];
    const float ox = blo(oo);
    const float oy = bhi(oo);
    const float2 pr = *(const float2*)&priors[(size_t)q * 8 + lv * 2];

    const int Wl = 128 >> lv;
    const float fW = (float)Wl;
    const float lx = fmaf(pr.x, fW, ox) - 0.5f;
    const float ly = fmaf(pr.y, fW, oy) - 0.5f;
    const float x0f = floorf(lx), y0f = floorf(ly);
    const float wx1 = lx - x0f, wy1 = ly - y0f;
    const float wx0 = 1.f - wx1, wy0 = 1.f - wy1;
    const int x0 = (int)x0f, y0 = (int)y0f;
    const int start = (int)((0x5400500040000000ull >> (16 * lv)) & 0xffff); // {0,16384,20480,21504}

    const bool vx0 = (x0 >= 0) & (x0 < Wl);
    const bool vx1 = (x0 + 1 >= 0) & (x0 + 1 < Wl);
    const bool vy0 = (y0 >= 0) & (y0 < Wl);
    const bool vy1 = (y0 + 1 >= 0) & (y0 + 1 < Wl);
    const int xc0 = min(max(x0, 0), Wl - 1);
    const int xc1 = min(max(x0 + 1, 0), Wl - 1);
    const int yc0 = min(max(y0, 0), Wl - 1);
    const int yc1 = min(max(y0 + 1, 0), Wl - 1);

    const int rt = start + yc0 * Wl;   // row bases (elements)
    const int rb = start + yc1 * Wl;

    int4 r0, r1;
    r0.x = (rt + xc0) * 64; r0.y = __float_as_int((vx0 & vy0) ? wN * wx0 * wy0 : 0.f);
    r0.z = (rt + xc1) * 64; r0.w = __float_as_int((vx1 & vy0) ? wN * wx1 * wy0 : 0.f);
    r1.x = (rb + xc0) * 64; r1.y = __float_as_int((vx0 & vy1) ? wN * wx0 * wy1 : 0.f);
    r1.z = (rb + xc1) * 64; r1.w = __float_as_int((vx1 & vy1) ? wN * wx1 * wy1 : 0.f);

    const int base = ql * 136 + j * 8;
    *(int4*)&s_rec[base] = r0;
    *(int4*)&s_rec[base + 4] = r1;
  }
  __syncthreads();

  // ---- phase 2 ----
  const int lane = t & 15;
  const int c = lane >> 2;        // corner: 0=TL 1=TR 2=BL 3=BR
  const int k = lane & 3;         // 16B chunk (8 channels)
  const char* plane_base = (const char*)val_bf + (size_t)plane * kS * 64 + k * 16;
  const int* rp = &s_rec[ql * 136 + c * 2];

  float a0 = 0.f, a1 = 0.f, a2 = 0.f, a3 = 0.f;
  float a4 = 0.f, a5 = 0.f, a6 = 0.f, a7 = 0.f;
#pragma unroll
  for (int j = 0; j < 16; ++j) {
    const int2 r = *(const int2*)&rp[j * 8];
    const float w = __int_as_float(r.y);
    const uint4 v = *(const uint4*)(plane_base + r.x);
    a0 = fmaf(w, blo(v.x), a0); a1 = fmaf(w, bhi(v.x), a1);
    a2 = fmaf(w, blo(v.y), a2); a3 = fmaf(w, bhi(v.y), a3);
    a4 = fmaf(w, blo(v.z), a4); a5 = fmaf(w, bhi(v.z), a5);
    a6 = fmaf(w, blo(v.w), a6); a7 = fmaf(w, bhi(v.w), a7);
  }

  // fold the 4 corners (lane bits 2-3)
#pragma unroll
  for (int m = 4; m <= 8; m <<= 1) {
    a0 += __shfl_xor(a0, m); a1 += __shfl_xor(a1, m);
    a2 += __shfl_xor(a2, m); a3 += __shfl_xor(a3, m);
    a4 += __shfl_xor(a4, m); a5 += __shfl_xor(a5, m);
    a6 += __shfl_xor(a6, m); a7 += __shfl_xor(a7, m);
  }

  if (c == 0) {
    const int c0 = h * 32 + k * 8;                    // ushort index in row
    const int dst = c0 ^ ((q & 7) << 3);
    uint4 o;
    o.x = (unsigned int)f2bf(a0) | ((unsigned int)f2bf(a1) << 16);
    o.y = (unsigned int)f2bf(a2) | ((unsigned int)f2bf(a3) << 16);
    o.z = (unsigned int)f2bf(a4) | ((unsigned int)f2bf(a5) << 16);
    o.w = (unsigned int)f2bf(a6) | ((unsigned int)f2bf(a7) << 16);
    *(uint4*)&wgt[(size_t)q * 256 + dst] = o;
  }
}

// ---------------------------------------------------------------------------
// launch
// ---------------------------------------------------------------------------
extern "C" void kernel_launch(void* const* d_in, const int* in_sizes, int n_in,
                              void* d_out, int out_size, void* d_ws, size_t ws_size,
                              hipStream_t stream) {
  const float* in_feats = (const float*)d_in[0];
  const float* priors   = (const float*)d_in[1];
  const float* sfeats   = (const float*)d_in[2];
  const float* W_off  = (const float*)d_in[5];
  const float* b_off  = (const float*)d_in[6];
  const float* W_attn = (const float*)d_in[7];
  const float* b_attn = (const float*)d_in[8];
  const float* W_val  = (const float*)d_in[9];
  const float* b_val  = (const float*)d_in[10];
  const float* W_out  = (const float*)d_in[11];
  const float* b_out  = (const float*)d_in[12];
  float* out = (float*)d_out;

  // workspace (bf16 ushorts), ~123 MB
  unsigned short* in_bf   = (unsigned short*)d_ws;          // kM*256 (swizzled)
  unsigned short* s_bf    = in_bf   + (size_t)kM * 256;     // kM*256 (swizzled)
  unsigned short* off_hm  = s_bf    + (size_t)kM * 256;     // [8][kM][32]
  unsigned short* attn_hm = off_hm  + (size_t)kM * 256;     // [8][kM][16]
  unsigned short* val_hm  = attn_hm + (size_t)kM * 128;     // [16][kS][32]
  unsigned short* wgt_bf  = val_hm  + (size_t)kM * 256;     // [kM][256] swizzled
  unsigned short* BtOff   = wgt_bf  + (size_t)kM * 256;     // 256*256 (BtOA rows 0-255)
  unsigned short* BtAttn  = BtOff   + 256 * 256;            // 128*256 (BtOA rows 256-383)
  unsigned short* BtVal   = BtAttn  + 128 * 256;            // 256*256
  unsigned short* BtOut   = BtVal   + 256 * 256;            // 256*256

  const dim3 blk(256);

  convprep<<<dim3(10992), blk, 0, stream>>>(
      in_feats, sfeats, in_bf, s_bf,
      W_off, W_attn, W_val, W_out, BtOff, BtAttn, BtVal, BtOut);

  gemm_lead<<<dim3(8 * 215), blk, 0, stream>>>(
      in_bf, s_bf, BtOff, BtVal, b_off, b_attn, b_val, off_hm, attn_hm, val_hm);

  msda_kernel<<<dim3(kM / 2), blk, 0, stream>>>(off_hm, attn_hm, val_hm, priors, wgt_bf);

  gemm_out<<<dim3(8 * 2 * 43), blk, 0, stream>>>(wgt_bf, BtOut, b_out, out);
}

// Round 7
// 145.969 us; speedup vs baseline: 1.0925x; 1.0336x over previous
//
#include <hip/hip_runtime.h>
#include <cstdint>

// Problem constants (fixed by setup_inputs)
constexpr int kB = 2;
constexpr int kN = 21760;
constexpr int kC = 256;
constexpr int kH = 8;
constexpr int kS = 21760;    // total sample-map area
constexpr int kM = kB * kN;  // 43520 rows
constexpr int kMT = 340;     // m-tiles (kM / 128)

typedef __attribute__((ext_vector_type(8))) short bf16x8;   // MFMA A/B frag (4 VGPR)
typedef __attribute__((ext_vector_type(4))) float f32x4;    // MFMA C/D frag
typedef __attribute__((ext_vector_type(8))) unsigned short us8;

__device__ __forceinline__ float bf2f(unsigned short u) {
  return __uint_as_float(((unsigned int)u) << 16);
}
__device__ __forceinline__ unsigned short f2bf(float f) {
  unsigned int u = __float_as_uint(f);
  u += 0x7fffu + ((u >> 16) & 1u);
  return (unsigned short)(u >> 16);
}
__device__ __forceinline__ float blo(unsigned int v) { return __uint_as_float(v << 16); }
__device__ __forceinline__ float bhi(unsigned int v) { return __uint_as_float(v & 0xffff0000u); }
__device__ __forceinline__ unsigned int cvt_pk_bf16(float lo, float hi) {
  unsigned int r;
  asm("v_cvt_pk_bf16_f32 %0, %1, %2" : "=v"(r) : "v"(lo), "v"(hi));
  return r;   // low ushort = bf16(lo), high ushort = bf16(hi)  [RNE]
}
__device__ __forceinline__ void gld_lds16(const unsigned short* g, unsigned short* l) {
  __builtin_amdgcn_global_load_lds(
      (const __attribute__((address_space(1))) unsigned int*)g,
      (__attribute__((address_space(3))) unsigned int*)l, 16, 0, 0);
}

// ---------------------------------------------------------------------------
// Fused convert + weight prep (unchanged from round 6).
// ---------------------------------------------------------------------------
__global__ __launch_bounds__(256) void convprep(
    const float* __restrict__ a, const float* __restrict__ b,
    unsigned short* __restrict__ da, unsigned short* __restrict__ db,
    const float* __restrict__ Woff, const float* __restrict__ Wattn,
    const float* __restrict__ Wval, const float* __restrict__ Wout,
    unsigned short* __restrict__ BtOff, unsigned short* __restrict__ BtAttn,
    unsigned short* __restrict__ BtVal, unsigned short* __restrict__ BtOut)
{
  const int bid = blockIdx.x;
  if (bid < 10880) {
    const int tid = bid * 256 + threadIdx.x;
    const int half = kM * 32;
    const float* src; unsigned short* dst; int id;
    if (tid < half) { src = a; dst = da; id = tid; }
    else            { src = b; dst = db; id = tid - half; }
    const int m = id >> 5;
    const int kb = (id & 31) * 8;
    const float4 x0 = *(const float4*)&src[(size_t)m * 256 + kb];
    const float4 x1 = *(const float4*)&src[(size_t)m * 256 + kb + 4];
    us8 o;
    o[0] = f2bf(x0.x); o[1] = f2bf(x0.y); o[2] = f2bf(x0.z); o[3] = f2bf(x0.w);
    o[4] = f2bf(x1.x); o[5] = f2bf(x1.y); o[6] = f2bf(x1.z); o[7] = f2bf(x1.w);
    *(us8*)&dst[(size_t)m * 256 + (kb ^ ((m & 7) << 3))] = o;
  } else {
    const int tid = (bid - 10880) * 256 + threadIdx.x;   // 896 rows * 32
    const int r = tid >> 5;
    const int kb = (tid & 31) * 8;
    const float* W; unsigned short* Bt; int n, Nn;
    if (r < 256)      { W = Woff;  Bt = BtOff;  n = r;       Nn = 256; }
    else if (r < 384) { W = Wattn; Bt = BtAttn; n = r - 256; Nn = 128; }
    else if (r < 640) { W = Wval;  Bt = BtVal;  n = r - 384; Nn = 256; }
    else              { W = Wout;  Bt = BtOut;  n = r - 640; Nn = 256; }
    us8 o;
#pragma unroll
    for (int i = 0; i < 8; ++i) o[i] = f2bf(W[(size_t)(kb + i) * Nn + n]);
    *(us8*)&Bt[(size_t)n * 256 + (kb ^ ((n & 7) << 3))] = o;
  }
}

// ---------------------------------------------------------------------------
// Shared MFMA tile core (unchanged, proven): A,Bt bf16 row-swizzled,
// 128x128 tile, BK=64, all staging via async global_load_lds.
// ---------------------------------------------------------------------------
__device__ __forceinline__ void mfma_tile_256(
    const unsigned short* __restrict__ A, const unsigned short* __restrict__ Bt,
    int m0, int n0, int t, unsigned short* As, unsigned short* Bs,
    f32x4 (&acc)[4][4])
{
  const int w = t >> 6, l = t & 63;
  const int wm = w >> 1, wn = w & 1;
  const int srow = l >> 3;
  const int skb  = (l & 7) * 8;

  for (int kt = 0; kt < 256; kt += 64) {
#pragma unroll
    for (int i = 0; i < 4; ++i) {
      const int c = i * 4 + w;
      const int row = c * 8 + srow;
      gld_lds16(A + (size_t)(m0 + row) * 256 + kt + skb, &As[c * 512]);
    }
#pragma unroll
    for (int i = 0; i < 4; ++i) {
      const int c = i * 4 + w;
      const int row = c * 8 + srow;
      gld_lds16(Bt + (size_t)(n0 + row) * 256 + kt + skb, &Bs[c * 512]);
    }
    __syncthreads();

#pragma unroll
    for (int s = 0; s < 2; ++s) {
      bf16x8 afr[4], bfr[4];
      const int kf = s * 32 + ((l >> 4) * 8);
#pragma unroll
      for (int i = 0; i < 4; ++i) {
        const int row = wm * 64 + i * 16 + (l & 15);
        afr[i] = *(const bf16x8*)&As[row * 64 + (kf ^ ((row & 7) << 3))];
      }
#pragma unroll
      for (int j = 0; j < 4; ++j) {
        const int col = wn * 64 + j * 16 + (l & 15);
        bfr[j] = *(const bf16x8*)&Bs[col * 64 + (kf ^ ((col & 7) << 3))];
      }
#pragma unroll
      for (int i = 0; i < 4; ++i)
#pragma unroll
        for (int j = 0; j < 4; ++j)
          acc[i][j] = __builtin_amdgcn_mfma_f32_16x16x32_bf16(afr[i], bfr[j], acc[i][j], 0, 0, 0);
    }
    __syncthreads();
  }
}

// ---------------------------------------------------------------------------
// Lead GEMM (unchanged from round 6).
// ---------------------------------------------------------------------------
__global__ __launch_bounds__(256) void gemm_lead(
    const unsigned short* __restrict__ in_bf,
    const unsigned short* __restrict__ s_bf,
    const unsigned short* __restrict__ BtOA,
    const unsigned short* __restrict__ BtVal,
    const float* __restrict__ b_off, const float* __restrict__ b_attn,
    const float* __restrict__ b_val,
    unsigned short* __restrict__ off_hm,
    unsigned short* __restrict__ attn_hm,
    unsigned short* __restrict__ val_hm)
{
  const int bid = blockIdx.x;
  const int x = bid & 7;
  const int slot = bid >> 3;
  int mode, nt, mh;
  if (slot < 129) { mode = 0; nt = slot % 3; mh = slot / 3; }
  else            { mode = 1; const int s2 = slot - 129; nt = s2 % 2; mh = s2 / 2; }
  const int m = mh * 8 + x;
  if (m >= kMT) return;
  const int m0 = m * 128, n0 = nt * 128;

  __shared__ unsigned short As[128 * 64];
  __shared__ unsigned short Bs[128 * 64];
  const int t = threadIdx.x;

  f32x4 acc[4][4] = {};
  mfma_tile_256(mode ? s_bf : in_bf, mode ? BtVal : BtOA, m0, n0, t, As, Bs, acc);

  const int w = t >> 6, l = t & 63;
  const int wm = w >> 1, wn = w & 1;
  const int lr = l >> 4;
#pragma unroll
  for (int j = 0; j < 4; ++j) {
    const int col = n0 + wn * 64 + j * 16 + (l & 15);
    const float bv = mode ? b_val[col] : (col < 256 ? b_off[col] : b_attn[col - 256]);
#pragma unroll
    for (int i = 0; i < 4; ++i) {
      const int rbase = m0 + wm * 64 + i * 16 + lr * 4;
#pragma unroll
      for (int r = 0; r < 4; ++r) {
        const float v = acc[i][j][r] + bv;
        const int row = rbase + r;
        if (mode == 1) {          // value head-major [16][kS][32]
          const int bb = row >= kS;
          const int s2 = row - bb * kS;
          val_hm[((size_t)(bb * 8 + (col >> 5)) * kS + s2) * 32 + (col & 31)] = f2bf(v);
        } else if (col < 256) {   // off head-major [8][kM][32]
          off_hm[((size_t)(col >> 5) * kM + row) * 32 + (col & 31)] = f2bf(v);
        } else {                  // attn head-major [8][kM][16]
          const int c2 = col - 256;
          attn_hm[((size_t)(c2 >> 4) * kM + row) * 16 + (c2 & 15)] = f2bf(v);
        }
      }
    }
  }
}

// ---------------------------------------------------------------------------
// Output GEMM (unchanged from round 6).
// ---------------------------------------------------------------------------
__global__ __launch_bounds__(256) void gemm_out(
    const unsigned short* __restrict__ wgt,
    const unsigned short* __restrict__ BtOut,
    const float* __restrict__ b_out,
    float* __restrict__ out)
{
  const int bid = blockIdx.x;
  const int x = bid & 7;
  const int slot = bid >> 3;
  const int nt = slot % 2;
  const int mh = slot / 2;
  const int m = mh * 8 + x;
  if (m >= kMT) return;
  const int m0 = m * 128, n0 = nt * 128;

  __shared__ unsigned short As[128 * 64];
  __shared__ unsigned short Bs[128 * 64];
  const int t = threadIdx.x;

  f32x4 acc[4][4] = {};
  mfma_tile_256(wgt, BtOut, m0, n0, t, As, Bs, acc);

  const int w = t >> 6, l = t & 63;
  const int wm = w >> 1, wn = w & 1;
  const int lr = l >> 4;
#pragma unroll
  for (int j = 0; j < 4; ++j) {
    const int col = n0 + wn * 64 + j * 16 + (l & 15);
    const float bv = b_out[col];
#pragma unroll
    for (int i = 0; i < 4; ++i) {
      const int rbase = m0 + wm * 64 + i * 16 + lr * 4;
#pragma unroll
      for (int r = 0; r < 4; ++r)
        out[(size_t)(rbase + r) * 256 + col] = acc[i][j][r] + bv;
    }
  }
}

// ---------------------------------------------------------------------------
// MSDA core, plane-partitioned. Phase 1 unchanged. Phase 2 restructured for
// memory-level parallelism: the round-6 version compiled to VGPR=32, which
// caps in-flight gathers at ~2-3 -> wave serializes into ~6 L2-latency
// rounds. Now: per batch of 8 samples, issue 8 ds_read_b64 records then 8
// independent global_load_dwordx4 (32 VGPRs of loads in flight), then do
// the 128 unpack+FMA. __launch_bounds__(256,4) lifts the register cap to
// 128 (16 waves/CU min) so the batch stays in registers.
// ---------------------------------------------------------------------------
__global__ __launch_bounds__(256, 4) void msda_kernel(
    const unsigned short* __restrict__ off_hm,   // [8][kM][32] bf16 head-major
    const unsigned short* __restrict__ attn_hm,  // [8][kM][16] bf16 head-major
    const unsigned short* __restrict__ val_bf,   // [16][kS][32] bf16 head-major
    const float* __restrict__ priors,            // [kM][8]
    unsigned short* __restrict__ wgt)            // [kM][256] bf16 swizzled
{
  __shared__ int s_rec[16 * 136];
  const int bid = blockIdx.x;
  const int plane = bid & 15;          // b*8 + h
  const int chunk = bid >> 4;
  const int b = plane >> 3, h = plane & 7;
  const int t = threadIdx.x;
  const int ql = t >> 4;
  const int q = b * kN + chunk * 16 + ql;

  { // ---- phase 1 ----
    const int j = t & 15;
    const int lv = j >> 2;

    const float lgt = bf2f(attn_hm[((size_t)h * kM + q) * 16 + j]);
    float mx = lgt;
#pragma unroll
    for (int m = 8; m; m >>= 1) mx = fmaxf(mx, __shfl_xor(mx, m, 16));
    const float p = __expf(lgt - mx);
    float sum = p;
#pragma unroll
    for (int m = 8; m; m >>= 1) sum += __shfl_xor(sum, m, 16);
    const float wN = p / sum;

    const unsigned int oo = *(const unsigned int*)&off_hm[((size_t)h * kM + q) * 32 + j * 2];
    const float ox = blo(oo);
    const float oy = bhi(oo);
    const float2 pr = *(const float2*)&priors[(size_t)q * 8 + lv * 2];

    const int Wl = 128 >> lv;
    const float fW = (float)Wl;
    const float lx = fmaf(pr.x, fW, ox) - 0.5f;
    const float ly = fmaf(pr.y, fW, oy) - 0.5f;
    const float x0f = floorf(lx), y0f = floorf(ly);
    const float wx1 = lx - x0f, wy1 = ly - y0f;
    const float wx0 = 1.f - wx1, wy0 = 1.f - wy1;
    const int x0 = (int)x0f, y0 = (int)y0f;
    const int start = (int)((0x5400500040000000ull >> (16 * lv)) & 0xffff); // {0,16384,20480,21504}

    const bool vx0 = (x0 >= 0) & (x0 < Wl);
    const bool vx1 = (x0 + 1 >= 0) & (x0 + 1 < Wl);
    const bool vy0 = (y0 >= 0) & (y0 < Wl);
    const bool vy1 = (y0 + 1 >= 0) & (y0 + 1 < Wl);
    const int xc0 = min(max(x0, 0), Wl - 1);
    const int xc1 = min(max(x0 + 1, 0), Wl - 1);
    const int yc0 = min(max(y0, 0), Wl - 1);
    const int yc1 = min(max(y0 + 1, 0), Wl - 1);

    const int rt = start + yc0 * Wl;   // row bases (elements)
    const int rb = start + yc1 * Wl;

    int4 r0, r1;
    r0.x = (rt + xc0) * 64; r0.y = __float_as_int((vx0 & vy0) ? wN * wx0 * wy0 : 0.f);
    r0.z = (rt + xc1) * 64; r0.w = __float_as_int((vx1 & vy0) ? wN * wx1 * wy0 : 0.f);
    r1.x = (rb + xc0) * 64; r1.y = __float_as_int((vx0 & vy1) ? wN * wx0 * wy1 : 0.f);
    r1.z = (rb + xc1) * 64; r1.w = __float_as_int((vx1 & vy1) ? wN * wx1 * wy1 : 0.f);

    const int base = ql * 136 + j * 8;
    *(int4*)&s_rec[base] = r0;
    *(int4*)&s_rec[base + 4] = r1;
  }
  __syncthreads();

  // ---- phase 2 (MLP-batched) ----
  const int lane = t & 15;
  const int c = lane >> 2;        // corner: 0=TL 1=TR 2=BL 3=BR
  const int k = lane & 3;         // 16B chunk (8 channels)
  const char* plane_base = (const char*)val_bf + (size_t)plane * kS * 64 + k * 16;
  const int* rp = &s_rec[ql * 136 + c * 2];

  float a0 = 0.f, a1 = 0.f, a2 = 0.f, a3 = 0.f;
  float a4 = 0.f, a5 = 0.f, a6 = 0.f, a7 = 0.f;
#pragma unroll
  for (int B = 0; B < 2; ++B) {
    int2 r[8];
#pragma unroll
    for (int j = 0; j < 8; ++j) r[j] = *(const int2*)&rp[(B * 8 + j) * 8];
    uint4 v[8];
#pragma unroll
    for (int j = 0; j < 8; ++j) v[j] = *(const uint4*)(plane_base + r[j].x);
#pragma unroll
    for (int j = 0; j < 8; ++j) {
      const float w = __int_as_float(r[j].y);
      a0 = fmaf(w, blo(v[j].x), a0); a1 = fmaf(w, bhi(v[j].x), a1);
      a2 = fmaf(w, blo(v[j].y), a2); a3 = fmaf(w, bhi(v[j].y), a3);
      a4 = fmaf(w, blo(v[j].z), a4); a5 = fmaf(w, bhi(v[j].z), a5);
      a6 = fmaf(w, blo(v[j].w), a6); a7 = fmaf(w, bhi(v[j].w), a7);
    }
  }

  // fold the 4 corners (lane bits 2-3)
#pragma unroll
  for (int m = 4; m <= 8; m <<= 1) {
    a0 += __shfl_xor(a0, m); a1 += __shfl_xor(a1, m);
    a2 += __shfl_xor(a2, m); a3 += __shfl_xor(a3, m);
    a4 += __shfl_xor(a4, m); a5 += __shfl_xor(a5, m);
    a6 += __shfl_xor(a6, m); a7 += __shfl_xor(a7, m);
  }

  if (c == 0) {
    const int c0 = h * 32 + k * 8;                    // ushort index in row
    const int dst = c0 ^ ((q & 7) << 3);
    uint4 o;
    o.x = cvt_pk_bf16(a0, a1);
    o.y = cvt_pk_bf16(a2, a3);
    o.z = cvt_pk_bf16(a4, a5);
    o.w = cvt_pk_bf16(a6, a7);
    *(uint4*)&wgt[(size_t)q * 256 + dst] = o;
  }
}

// ---------------------------------------------------------------------------
// launch
// ---------------------------------------------------------------------------
extern "C" void kernel_launch(void* const* d_in, const int* in_sizes, int n_in,
                              void* d_out, int out_size, void* d_ws, size_t ws_size,
                              hipStream_t stream) {
  const float* in_feats = (const float*)d_in[0];
  const float* priors   = (const float*)d_in[1];
  const float* sfeats   = (const float*)d_in[2];
  const float* W_off  = (const float*)d_in[5];
  const float* b_off  = (const float*)d_in[6];
  const float* W_attn = (const float*)d_in[7];
  const float* b_attn = (const float*)d_in[8];
  const float* W_val  = (const float*)d_in[9];
  const float* b_val  = (const float*)d_in[10];
  const float* W_out  = (const float*)d_in[11];
  const float* b_out  = (const float*)d_in[12];
  float* out = (float*)d_out;

  // workspace (bf16 ushorts), ~123 MB
  unsigned short* in_bf   = (unsigned short*)d_ws;          // kM*256 (swizzled)
  unsigned short* s_bf    = in_bf   + (size_t)kM * 256;     // kM*256 (swizzled)
  unsigned short* off_hm  = s_bf    + (size_t)kM * 256;     // [8][kM][32]
  unsigned short* attn_hm = off_hm  + (size_t)kM * 256;     // [8][kM][16]
  unsigned short* val_hm  = attn_hm + (size_t)kM * 128;     // [16][kS][32]
  unsigned short* wgt_bf  = val_hm  + (size_t)kM * 256;     // [kM][256] swizzled
  unsigned short* BtOff   = wgt_bf  + (size_t)kM * 256;     // 256*256 (BtOA rows 0-255)
  unsigned short* BtAttn  = BtOff   + 256 * 256;            // 128*256 (BtOA rows 256-383)
  unsigned short* BtVal   = BtAttn  + 128 * 256;            // 256*256
  unsigned short* BtOut   = BtVal   + 256 * 256;            // 256*256

  const dim3 blk(256);

  convprep<<<dim3(10992), blk, 0, stream>>>(
      in_feats, sfeats, in_bf, s_bf,
      W_off, W_attn, W_val, W_out, BtOff, BtAttn, BtVal, BtOut);

  gemm_lead<<<dim3(8 * 215), blk, 0, stream>>>(
      in_bf, s_bf, BtOff, BtVal, b_off, b_attn, b_val, off_hm, attn_hm, val_hm);

  msda_kernel<<<dim3(kM / 2), blk, 0, stream>>>(off_hm, attn_hm, val_hm, priors, wgt_bf);

  gemm_out<<<dim3(8 * 2 * 43), blk, 0, stream>>>(wgt_bf, BtOut, b_out, out);
}